// Round 1
// baseline (35.782 us; speedup 1.0000x reference)
//
#include <hip/hip_runtime.h>
#include <hip/hip_bf16.h>

#define BB   8
#define CC   128
#define TLEN 8192
#define TBLK 64

typedef __attribute__((ext_vector_type(8))) short short8;
typedef __attribute__((ext_vector_type(4))) float f32x4;

__device__ __forceinline__ short f2bf(float f) {
    union { float f; unsigned u; } v; v.f = f;
    return (short)((v.u + 0x7FFFu + ((v.u >> 16) & 1u)) >> 16);
}
__device__ __forceinline__ float bf2f(unsigned short h) {
    union { unsigned u; float f; } v; v.u = ((unsigned)h) << 16;
    return v.f;
}

__global__ __launch_bounds__(256, 3)
void cfm_main(const float* __restrict__ x1, const float* __restrict__ tsm,
              const float* __restrict__ z, const float* __restrict__ W,
              const float* __restrict__ blin, const int* __restrict__ xlens,
              const int* __restrict__ plens, float* __restrict__ out)
{
    __shared__ short    ylds[TBLK][136];   // y tile, bf16, transposed [t][c], row=272B (16B aligned)
    __shared__ unsigned uw[TBLK][137];     // packed (w<<16)|u bf16, [t][c]
    __shared__ float    red[256];

    const int b    = blockIdx.y;
    const int t0   = blockIdx.x * TBLK;
    const int tid  = threadIdx.x;
    const int lane = tid & 63;
    const int wid  = tid >> 6;
    const int r15  = lane & 15;
    const int q4   = lane >> 4;

    const float ts  = tsm[b];
    const int   pl  = plens[b];
    const int   xl  = xlens[b];
    const float oms = 0.999999f;           // 1 - sigma
    const float cz  = 1.0f - oms * ts;
    const float cx  = ts;

    // ---- A fragments: W[d][c] rows for this wave, f32 -> bf16, once per block ----
    short8 afrag[2][4];                    // [d-tile 16][k-step c/32]
    #pragma unroll
    for (int dt = 0; dt < 2; ++dt) {
        const int row = wid * 32 + dt * 16 + r15;
        #pragma unroll
        for (int ks = 0; ks < 4; ++ks) {
            const float4 w0 = *reinterpret_cast<const float4*>(W + row * CC + ks * 32 + q4 * 8);
            const float4 w1 = *reinterpret_cast<const float4*>(W + row * CC + ks * 32 + q4 * 8 + 4);
            short8 a;
            a[0] = f2bf(w0.x); a[1] = f2bf(w0.y); a[2] = f2bf(w0.z); a[3] = f2bf(w0.w);
            a[4] = f2bf(w1.x); a[5] = f2bf(w1.y); a[6] = f2bf(w1.z); a[7] = f2bf(w1.w);
            afrag[dt][ks] = a;
        }
    }

    // ---- stage y (bf16, [t][c]) and packed u/w, coalesced float4 global reads ----
    {
        const int tcol = (tid & 15) * 4;
        const int crow = tid >> 4;
        #pragma unroll
        for (int p = 0; p < 8; ++p) {
            const int c = p * 16 + crow;
            const size_t g = (size_t)(b * CC + c) * TLEN + t0 + tcol;
            const float4 xv = *reinterpret_cast<const float4*>(x1 + g);
            const float4 zv = *reinterpret_cast<const float4*>(z + g);
            const float xa[4] = {xv.x, xv.y, xv.z, xv.w};
            const float za[4] = {zv.x, zv.y, zv.z, zv.w};
            #pragma unroll
            for (int j = 0; j < 4; ++j) {
                const int t = t0 + tcol + j;
                float y = cz * za[j] + cx * xa[j];
                if (t < pl) y = 0.0f;
                ylds[tcol + j][c] = f2bf(y);
                const float w = oms * za[j];
                const float u = xa[j] - w;
                uw[tcol + j][c] = (unsigned)(unsigned short)f2bf(u)
                                | ((unsigned)(unsigned short)f2bf(w) << 16);
            }
        }
    }
    __syncthreads();

    // ---- MFMA: out-tile 128d x 64t, wave w owns d in [32w, 32w+32) ----
    f32x4 acc[2][4];
    #pragma unroll
    for (int dt = 0; dt < 2; ++dt)
        #pragma unroll
        for (int tt = 0; tt < 4; ++tt)
            acc[dt][tt] = (f32x4){0.f, 0.f, 0.f, 0.f};

    #pragma unroll
    for (int ks = 0; ks < 4; ++ks) {
        #pragma unroll
        for (int tt = 0; tt < 4; ++tt) {
            const short8 bfrag =
                *reinterpret_cast<const short8*>(&ylds[tt * 16 + r15][ks * 32 + q4 * 8]);
            acc[0][tt] = __builtin_amdgcn_mfma_f32_16x16x32_bf16(afrag[0][ks], bfrag, acc[0][tt], 0, 0, 0);
            acc[1][tt] = __builtin_amdgcn_mfma_f32_16x16x32_bf16(afrag[1][ks], bfrag, acc[1][tt], 0, 0, 0);
        }
    }

    // ---- epilogue: bias, out2 store, masked loss partials ----
    float bl[2][4];
    #pragma unroll
    for (int dt = 0; dt < 2; ++dt)
        #pragma unroll
        for (int rr = 0; rr < 4; ++rr)
            bl[dt][rr] = blin[wid * 32 + dt * 16 + q4 * 4 + rr];

    float lsum = 0.0f;
    #pragma unroll
    for (int dt = 0; dt < 2; ++dt) {
        #pragma unroll
        for (int tt = 0; tt < 4; ++tt) {
            const int tl = tt * 16 + r15;
            const int t  = t0 + tl;
            const bool lm = (t >= pl) & (t < xl);
            #pragma unroll
            for (int rr = 0; rr < 4; ++rr) {
                const int d = wid * 32 + dt * 16 + q4 * 4 + rr;
                const unsigned uwv = uw[tl][d];
                const float u = bf2f((unsigned short)(uwv & 0xFFFFu));
                const float w = bf2f((unsigned short)(uwv >> 16));
                const float ov = acc[dt][tt][rr] + bl[dt][rr];
                out[1 + (size_t)(b * CC + d) * TLEN + t] = ov + w;
                if (lm) { const float df = ov - u; lsum += df * df; }
            }
        }
    }
    lsum *= 1.0f / (8.0f * 128.0f * (float)(xl - pl));

    // ---- block reduce + atomic into loss slot ----
    red[tid] = lsum;
    __syncthreads();
    for (int s = 128; s >= 1; s >>= 1) {
        if (tid < s) red[tid] += red[tid + s];
        __syncthreads();
    }
    if (tid == 0) atomicAdd(out, red[0]);
}

extern "C" void kernel_launch(void* const* d_in, const int* in_sizes, int n_in,
                              void* d_out, int out_size, void* d_ws, size_t ws_size,
                              hipStream_t stream) {
    const float* x1   = (const float*)d_in[0];
    // d_in[1] = mu (unused), d_in[2] = style (unused)
    const float* tsm  = (const float*)d_in[3];
    const float* z    = (const float*)d_in[4];
    const float* W    = (const float*)d_in[5];
    const float* blin = (const float*)d_in[6];
    const int*   xlens = (const int*)d_in[7];
    const int*   plens = (const int*)d_in[8];
    float* out = (float*)d_out;

    hipMemsetAsync(out, 0, sizeof(float), stream);   // zero loss accumulator
    dim3 grid(TLEN / TBLK, BB);
    cfm_main<<<grid, 256, 0, stream>>>(x1, tsm, z, W, blin, xlens, plens, out);
}

// Round 2
// 31.590 us; speedup vs baseline: 1.1327x; 1.1327x over previous
//
#include <hip/hip_runtime.h>
#include <hip/hip_bf16.h>

#define BB   8
#define CC   128
#define TLEN 8192
#define TBLK 32
#define NTBLK (TLEN / TBLK)          // 256 t-tiles
#define NBLOCKS (NTBLK * BB)         // 2048 blocks
// d_ws layout: [0 .. 8KB)  : 2048 f32 loss partials
//              [8KB .. 40KB): W as bf16 in MFMA A-frag order
#define WS_W_OFF 8192

typedef __attribute__((ext_vector_type(8))) short short8;
typedef __attribute__((ext_vector_type(4))) float f32x4;

__device__ __forceinline__ short f2bf(float f) {
    union { float f; unsigned u; } v; v.f = f;
    return (short)((v.u + 0x7FFFu + ((v.u >> 16) & 1u)) >> 16);
}
__device__ __forceinline__ float bf2f(unsigned short h) {
    union { unsigned u; float f; } v; v.u = ((unsigned)h) << 16;
    return v.f;
}

// ---- prep: W f32 [128][128] -> bf16 fragments in exact A-operand order ----
// frag element (dtile 0..7, ks 0..3, lane 0..63, e 0..7):
//   row = dtile*16 + (lane&15), col = ks*32 + (lane>>4)*8 + e
__global__ void prep_w(const float* __restrict__ W, short* __restrict__ wsW) {
    const int gid   = blockIdx.x * 256 + threadIdx.x;   // 0..2047
    const int lane  = gid & 63;
    const int ksdt  = gid >> 6;                          // 0..31
    const int dtile = ksdt >> 2;
    const int ks    = ksdt & 3;
    const int row   = dtile * 16 + (lane & 15);
    const int col0  = ks * 32 + (lane >> 4) * 8;
    short8 a;
    #pragma unroll
    for (int e = 0; e < 8; ++e) a[e] = f2bf(W[row * CC + col0 + e]);
    reinterpret_cast<short8*>(wsW)[gid] = a;
}

__global__ __launch_bounds__(256, 5)
void cfm_main(const float* __restrict__ x1, const float* __restrict__ tsm,
              const float* __restrict__ z, const short* __restrict__ wsW,
              const float* __restrict__ blin, const int* __restrict__ xlens,
              const int* __restrict__ plens, float* __restrict__ out,
              float* __restrict__ wsPart)
{
    __shared__ short    ylds[TBLK][136];   // y tile bf16, [t][c], 272B rows (16B-aligned)
    __shared__ unsigned uw[TBLK][137];     // packed (w<<16)|u bf16, [t][c]
    __shared__ float    red[4];

    const int b    = blockIdx.y;
    const int t0   = blockIdx.x * TBLK;
    const int tid  = threadIdx.x;
    const int lane = tid & 63;
    const int wid  = tid >> 6;
    const int r15  = lane & 15;
    const int q4   = lane >> 4;

    const float ts  = tsm[b];
    const int   pl  = plens[b];
    const int   xl  = xlens[b];
    const float oms = 0.999999f;           // 1 - sigma
    const float cz  = 1.0f - oms * ts;
    const float cx  = ts;

    // ---- A fragments: pre-converted bf16, coalesced 16B loads, no cvt ----
    short8 afrag[2][4];
    {
        const short8* wf = reinterpret_cast<const short8*>(wsW);
        #pragma unroll
        for (int dt = 0; dt < 2; ++dt)
            #pragma unroll
            for (int ks = 0; ks < 4; ++ks)
                afrag[dt][ks] = wf[((wid * 2 + dt) * 4 + ks) * 64 + lane];
    }

    // ---- stage y (bf16, [t][c]) + packed u/w; coalesced float4 reads ----
    {
        const int tcol = (tid & 7) * 4;    // t offset
        const int crow = tid >> 3;         // 0..31
        #pragma unroll
        for (int p = 0; p < 4; ++p) {
            const int c = p * 32 + crow;
            const size_t g = (size_t)(b * CC + c) * TLEN + t0 + tcol;
            const float4 xv = *reinterpret_cast<const float4*>(x1 + g);
            const float4 zv = *reinterpret_cast<const float4*>(z + g);
            const float xa[4] = {xv.x, xv.y, xv.z, xv.w};
            const float za[4] = {zv.x, zv.y, zv.z, zv.w};
            #pragma unroll
            for (int j = 0; j < 4; ++j) {
                const int t = t0 + tcol + j;
                float y = cz * za[j] + cx * xa[j];
                if (t < pl) y = 0.0f;
                ylds[tcol + j][c] = f2bf(y);
                const float w = oms * za[j];
                const float u = xa[j] - w;
                uw[tcol + j][c] = (unsigned)(unsigned short)f2bf(u)
                                | ((unsigned)(unsigned short)f2bf(w) << 16);
            }
        }
    }
    __syncthreads();

    // ---- MFMA: 128d x 32t tile; wave w owns d in [32w, 32w+32) ----
    f32x4 acc[2][2];
    #pragma unroll
    for (int dt = 0; dt < 2; ++dt)
        #pragma unroll
        for (int tt = 0; tt < 2; ++tt)
            acc[dt][tt] = (f32x4){0.f, 0.f, 0.f, 0.f};

    #pragma unroll
    for (int ks = 0; ks < 4; ++ks) {
        #pragma unroll
        for (int tt = 0; tt < 2; ++tt) {
            const short8 bfrag =
                *reinterpret_cast<const short8*>(&ylds[tt * 16 + r15][ks * 32 + q4 * 8]);
            acc[0][tt] = __builtin_amdgcn_mfma_f32_16x16x32_bf16(afrag[0][ks], bfrag, acc[0][tt], 0, 0, 0);
            acc[1][tt] = __builtin_amdgcn_mfma_f32_16x16x32_bf16(afrag[1][ks], bfrag, acc[1][tt], 0, 0, 0);
        }
    }

    // ---- epilogue: bias, out2 store, masked loss partials ----
    float bl[2][4];
    #pragma unroll
    for (int dt = 0; dt < 2; ++dt)
        #pragma unroll
        for (int rr = 0; rr < 4; ++rr)
            bl[dt][rr] = blin[wid * 32 + dt * 16 + q4 * 4 + rr];

    float lsum = 0.0f;
    #pragma unroll
    for (int dt = 0; dt < 2; ++dt) {
        #pragma unroll
        for (int tt = 0; tt < 2; ++tt) {
            const int tl = tt * 16 + r15;
            const int t  = t0 + tl;
            const bool lm = (t >= pl) & (t < xl);
            #pragma unroll
            for (int rr = 0; rr < 4; ++rr) {
                const int d = wid * 32 + dt * 16 + q4 * 4 + rr;
                const unsigned uwv = uw[tl][d];
                const float u = bf2f((unsigned short)(uwv & 0xFFFFu));
                const float w = bf2f((unsigned short)(uwv >> 16));
                const float ov = acc[dt][tt][rr] + bl[dt][rr];
                out[1 + (size_t)(b * CC + d) * TLEN + t] = ov + w;
                if (lm) { const float df = ov - u; lsum += df * df; }
            }
        }
    }

    // ---- per-wave shuffle reduce -> per-block partial (scaled) ----
    #pragma unroll
    for (int off = 32; off >= 1; off >>= 1) lsum += __shfl_down(lsum, off);
    if (lane == 0) red[wid] = lsum;
    __syncthreads();
    if (tid == 0) {
        const float scale = 1.0f / (1024.0f * (float)(xl - pl));  // 1/(B*C*(xl-pl))
        wsPart[blockIdx.y * gridDim.x + blockIdx.x] =
            (red[0] + red[1] + red[2] + red[3]) * scale;
    }
}

// ---- final: sum 2048 partials -> out[0] ----
__global__ void final_red(const float* __restrict__ wsPart, float* __restrict__ out) {
    __shared__ float red[4];
    const int tid = threadIdx.x;
    float s = 0.0f;
    #pragma unroll
    for (int i = 0; i < NBLOCKS / 256; ++i) s += wsPart[tid + i * 256];
    #pragma unroll
    for (int off = 32; off >= 1; off >>= 1) s += __shfl_down(s, off);
    if ((tid & 63) == 0) red[tid >> 6] = s;
    __syncthreads();
    if (tid == 0) out[0] = red[0] + red[1] + red[2] + red[3];
}

extern "C" void kernel_launch(void* const* d_in, const int* in_sizes, int n_in,
                              void* d_out, int out_size, void* d_ws, size_t ws_size,
                              hipStream_t stream) {
    const float* x1    = (const float*)d_in[0];
    // d_in[1] = mu (unused), d_in[2] = style (unused)
    const float* tsm   = (const float*)d_in[3];
    const float* z     = (const float*)d_in[4];
    const float* W     = (const float*)d_in[5];
    const float* blin  = (const float*)d_in[6];
    const int*   xlens = (const int*)d_in[7];
    const int*   plens = (const int*)d_in[8];
    float* out = (float*)d_out;

    float* wsPart = (float*)d_ws;
    short* wsW    = (short*)((char*)d_ws + WS_W_OFF);

    prep_w<<<8, 256, 0, stream>>>(W, wsW);
    dim3 grid(NTBLK, BB);
    cfm_main<<<grid, 256, 0, stream>>>(x1, tsm, z, wsW, blin, xlens, plens, out, wsPart);
    final_red<<<1, 256, 0, stream>>>(wsPart, out);
}